// Round 6
// baseline (121.475 us; speedup 1.0000x reference)
//
#include <hip/hip_runtime.h>
#include <math.h>

#define C_   256
#define WH   4096

typedef _Float16 f16x8 __attribute__((ext_vector_type(8)));
typedef float    f32x4 __attribute__((ext_vector_type(4)));

// ---------------- workspace layout (floats) ----------------
// qbn   : [16][16][4096]          @ 0          (1,048,576)
// kkbn  : [16][16][4096]          @ 1,048,576  (1,048,576)
// pstats: [256 rows][16 chunk][2] @ 2,097,152  (8,192)
// Wt    : [16][4096]              @ 2,105,344  (65,536)
// lam   : [16][16][64]            @ 2,170,880  (16,384)   (atomic-accumulated)

// ---- q/k 1x1 projections + BN + per-chunk softmax partials (blocks 0..255)
//      + Wt generation + lam zeroing (blocks 256..319). ----
__global__ __launch_bounds__(512) void proj_kernel(
    const float* __restrict__ x,
    const float* __restrict__ qw, const float* __restrict__ kw,
    const float* __restrict__ qg, const float* __restrict__ qb,
    const float* __restrict__ qm, const float* __restrict__ qv,
    const float* __restrict__ kg, const float* __restrict__ kb,
    const float* __restrict__ km, const float* __restrict__ kv,
    const float* __restrict__ emb,
    float* __restrict__ qbn, float* __restrict__ kkbn,
    float* __restrict__ pstats, float* __restrict__ Wt,
    float* __restrict__ lam)
{
    if (blockIdx.x >= 256) {
        // ---- Wt: summed spatial weight of the positional conv ----
        int wb = blockIdx.x - 256;
        // zero lam slice (re-zeroed every launch; ut atomically accumulates)
        if (threadIdx.x < 256) lam[wb * 256 + threadIdx.x] = 0.f;
        int hk = wb >> 2, quarter = wb & 3;
        int h = hk >> 2, k = hk & 3;
        const float* e = emb + (size_t)(k * 4 + h) * 529;   // emb[k][h][0][0][i][j]
        __shared__ float colsum[23][64];
        for (int t2 = threadIdx.x; t2 < 23 * 64; t2 += 512) {
            int i = t2 / 64, q = t2 % 64;
            int jlo = max(0, q - 52), jhi = min(22, q + 11);
            float s = 0.f;
            for (int j = jlo; j <= jhi; ++j) s += e[i * 23 + j];
            colsum[i][q] = s;
        }
        __syncthreads();
        for (int tt = threadIdx.x; tt < 1024; tt += 512) {
            int t2 = quarter * 1024 + tt;
            int p = t2 >> 6, q = t2 & 63;
            int ilo = max(0, p - 52), ihi = min(22, p + 11);
            float s = 0.f;
            for (int i = ilo; i <= ihi; ++i) s += colsum[i][q];
            Wt[(size_t)hk * WH + t2] = s;
        }
        return;
    }

    int t = threadIdx.x;
    int b = blockIdx.x >> 4, chunk = blockIdx.x & 15;
    int lane = t & 63;
    int og = __builtin_amdgcn_readfirstlane(t >> 6);   // 0..7, wave-uniform
    int isK = og >> 2;
    int o4 = (og & 3) * 4;
    int xy = chunk * 256 + lane * 4;

    const float* wsrc = isK ? kw : qw;
    const float* w0 = wsrc + (size_t)(o4 + 0) * 256;
    const float* w1 = wsrc + (size_t)(o4 + 1) * 256;
    const float* w2 = wsrc + (size_t)(o4 + 2) * 256;
    const float* w3 = wsrc + (size_t)(o4 + 3) * 256;

    float4 a0 = {0,0,0,0}, a1 = {0,0,0,0}, a2 = {0,0,0,0}, a3 = {0,0,0,0};
    const float* xb = x + (size_t)b * C_ * WH + xy;
#pragma unroll 8
    for (int c = 0; c < 256; ++c) {
        float4 xv = *(const float4*)(xb + (size_t)c * WH);
        float f0 = w0[c], f1 = w1[c], f2 = w2[c], f3 = w3[c];
        a0.x += xv.x*f0; a0.y += xv.y*f0; a0.z += xv.z*f0; a0.w += xv.w*f0;
        a1.x += xv.x*f1; a1.y += xv.y*f1; a1.z += xv.z*f1; a1.w += xv.w*f1;
        a2.x += xv.x*f2; a2.y += xv.y*f2; a2.z += xv.z*f2; a2.w += xv.w*f2;
        a3.x += xv.x*f3; a3.y += xv.y*f3; a3.z += xv.z*f3; a3.w += xv.w*f3;
    }
    float4 acc4[4] = {a0, a1, a2, a3};

    if (!isK) {
#pragma unroll
        for (int i = 0; i < 4; ++i) {
            int hk = o4 + i;
            float s  = qg[hk] * rsqrtf(qv[hk] + 1e-5f);
            float tq = qb[hk] - qm[hk] * s;
            float4 a = acc4[i], o;
            o.x = a.x * s + tq; o.y = a.y * s + tq;
            o.z = a.z * s + tq; o.w = a.w * s + tq;
            *(float4*)(qbn + ((size_t)b * 16 + hk) * WH + xy) = o;
        }
    } else {
#pragma unroll
        for (int i = 0; i < 4; ++i) {
            int hk = o4 + i;
            float s2 = kg[hk] * rsqrtf(kv[hk] + 1e-5f);
            float tk = kb[hk] - km[hk] * s2;
            float4 a = acc4[i], o;
            o.x = a.x * s2 + tk; o.y = a.y * s2 + tk;
            o.z = a.z * s2 + tk; o.w = a.w * s2 + tk;
            *(float4*)(kkbn + ((size_t)b * 16 + hk) * WH + xy) = o;
            float m = fmaxf(fmaxf(o.x, o.y), fmaxf(o.z, o.w));
#pragma unroll
            for (int off = 32; off; off >>= 1) m = fmaxf(m, __shfl_xor(m, off, 64));
            float e = __expf(o.x - m) + __expf(o.y - m) + __expf(o.z - m) + __expf(o.w - m);
#pragma unroll
            for (int off = 32; off; off >>= 1) e += __shfl_xor(e, off, 64);
            if (lane == 0) {
                float* ps = pstats + ((size_t)(b * 16 + hk) * 16 + chunk) * 2;
                ps[0] = m; ps[1] = e;
            }
        }
    }
}

// ---- U/T contractions via fp16 MFMA (fp32 accumulate) + fused lambda.
// Grid 512 = (b, s5 of 128 xy), 2 blocks/CU. After the MFMA loop, U and T
// rows are merged IN-REGISTER (same lane, same column), written to a 16x256
// fp32 LDS tile, and each block contracts with vw (global, L2-resident) and
// atomicAdds its 16x64 lambda contribution. Mpart + lam_kernel eliminated. ----
__global__ __launch_bounds__(512) void ut_kernel(
    const float* __restrict__ x, const float* __restrict__ kkbn,
    const float* __restrict__ pstats, const float* __restrict__ Wt,
    const float* __restrict__ vw, float* __restrict__ lam)
{
    __shared__ _Float16 xls[256][72];   // 36,864 B : X rows (c), 64 k per chunk
    __shared__ _Float16 wls[32][72];    //  4,608 B : W rows (r), 64 k per chunk
    __shared__ float st[32];            // M, 1/S per sm row
    __shared__ float msum[16][260];     // 16,640 B : merged U+T rows (fp32)
    int t = threadIdx.x;
    int b = blockIdx.x >> 5, s5 = blockIdx.x & 31;
    int xys0 = s5 * 128;
    int lane = t & 63;
    int wid = __builtin_amdgcn_readfirstlane(t >> 6);   // 0..7
    int r16 = lane & 15, g = lane >> 4;
    int n0 = wid * 32;

    // ---- inline softmax-stats combine: thread r<16 handles row r ----
    if (t < 16) {
        const float* ps = pstats + (size_t)(b * 16 + t) * 32;
        float M = ps[0];
#pragma unroll
        for (int ch = 1; ch < 16; ++ch) M = fmaxf(M, ps[ch * 2]);
        float S = 0.f;
#pragma unroll
        for (int ch = 0; ch < 16; ++ch) S += ps[ch * 2 + 1] * __expf(ps[ch * 2] - M);
        st[2 * t]     = M;
        st[2 * t + 1] = 1.f / S;
    }

    // staging coords
    int sc = t >> 1, shalf = t & 1;                 // x: row sc, 32-col half
    int wr = t >> 3, wco = (t & 7) * 8;             // w: row wr (t<256 only)

    f32x4 acc00 = {0.f,0.f,0.f,0.f}, acc01 = {0.f,0.f,0.f,0.f};
    f32x4 acc10 = {0.f,0.f,0.f,0.f}, acc11 = {0.f,0.f,0.f,0.f};

    for (int ch = 0; ch < 2; ++ch) {
        int kbase = xys0 + ch * 64;
        __syncthreads();                            // st[] visible / prev reads done
        {   // stage X: 256 rows x 64 k  (thread: row sc, cols shalf*32..+31)
            const float* xp = x + ((size_t)b * C_ + sc) * WH + kbase + shalf * 32;
#pragma unroll
            for (int j = 0; j < 4; ++j) {
                float4 u  = *(const float4*)(xp + j * 8);
                float4 u2 = *(const float4*)(xp + j * 8 + 4);
                f16x8 o;
                o[0] = (_Float16)u.x;  o[1] = (_Float16)u.y;
                o[2] = (_Float16)u.z;  o[3] = (_Float16)u.w;
                o[4] = (_Float16)u2.x; o[5] = (_Float16)u2.y;
                o[6] = (_Float16)u2.z; o[7] = (_Float16)u2.w;
                *(f16x8*)&xls[sc][shalf * 32 + j * 8] = o;
            }
        }
        if (t < 256) {  // stage W: rows 0..15 = sm(kkbn), 16..31 = Wt
            f16x8 o;
            if (wr < 16) {
                float wm   = st[2 * wr];
                float winv = st[2 * wr + 1];
                const float* src = kkbn + ((size_t)b * 16 + wr) * WH + kbase + wco;
                float4 u  = *(const float4*)(src);
                float4 u2 = *(const float4*)(src + 4);
                o[0] = (_Float16)(__expf(u.x  - wm) * winv);
                o[1] = (_Float16)(__expf(u.y  - wm) * winv);
                o[2] = (_Float16)(__expf(u.z  - wm) * winv);
                o[3] = (_Float16)(__expf(u.w  - wm) * winv);
                o[4] = (_Float16)(__expf(u2.x - wm) * winv);
                o[5] = (_Float16)(__expf(u2.y - wm) * winv);
                o[6] = (_Float16)(__expf(u2.z - wm) * winv);
                o[7] = (_Float16)(__expf(u2.w - wm) * winv);
            } else {
                const float* src = Wt + (size_t)(wr - 16) * WH + kbase + wco;
                float4 u  = *(const float4*)(src);
                float4 u2 = *(const float4*)(src + 4);
                o[0] = (_Float16)u.x;  o[1] = (_Float16)u.y;
                o[2] = (_Float16)u.z;  o[3] = (_Float16)u.w;
                o[4] = (_Float16)u2.x; o[5] = (_Float16)u2.y;
                o[6] = (_Float16)u2.z; o[7] = (_Float16)u2.w;
            }
            *(f16x8*)&wls[wr][wco] = o;
        }
        __syncthreads();                            // tile visible
#pragma unroll
        for (int s = 0; s < 2; ++s) {
            int koff = s * 32 + g * 8;
            f16x8 A0 = *(const f16x8*)&wls[r16     ][koff];
            f16x8 A1 = *(const f16x8*)&wls[16 + r16][koff];
            f16x8 B0 = *(const f16x8*)&xls[n0 + r16     ][koff];
            f16x8 B1 = *(const f16x8*)&xls[n0 + 16 + r16][koff];
            acc00 = __builtin_amdgcn_mfma_f32_16x16x32_f16(A0, B0, acc00, 0, 0, 0);
            acc01 = __builtin_amdgcn_mfma_f32_16x16x32_f16(A0, B1, acc01, 0, 0, 0);
            acc10 = __builtin_amdgcn_mfma_f32_16x16x32_f16(A1, B0, acc10, 0, 0, 0);
            acc11 = __builtin_amdgcn_mfma_f32_16x16x32_f16(A1, B1, acc11, 0, 0, 0);
        }
    }

    // ---- merge U (rows r) + T (rows 16+r) in-register -> msum[16][256] ----
    // D layout: row = g*4 + reg, col = n0 (+16) + r16
    {
        int colA = n0 + r16, colB = n0 + 16 + r16;
        int row0 = g * 4;
#pragma unroll
        for (int rr = 0; rr < 4; ++rr) {
            msum[row0 + rr][colA] = acc00[rr] + acc10[rr];
            msum[row0 + rr][colB] = acc01[rr] + acc11[rr];
        }
    }
    __syncthreads();

    // ---- block-local lambda contribution: lam[b,r,v] += sum_c msum[r][c]*vw[h,v,c]
    // thread = (r = t>>5, v = t&31 handling {v, v+32}); msum reads broadcast. ----
    {
        int r = t >> 5;          // 0..15
        int v = t & 31;
        int h = r >> 2;
        const float* vwa = vw + ((size_t)h * 64 + v) * 256;
        const float* vwb = vwa + 32 * 256;
        float la = 0.f, lb2 = 0.f;
#pragma unroll 8
        for (int c4 = 0; c4 < 64; ++c4) {
            float4 m4 = *(const float4*)&msum[r][c4 * 4];
            float4 wa = *(const float4*)(vwa + c4 * 4);
            float4 wb = *(const float4*)(vwb + c4 * 4);
            la  += m4.x*wa.x + m4.y*wa.y + m4.z*wa.z + m4.w*wa.w;
            lb2 += m4.x*wb.x + m4.y*wb.y + m4.z*wb.z + m4.w*wb.w;
        }
        float* lp = lam + ((size_t)b * 16 + r) * 64 + v;
        atomicAdd(lp,      la);
        atomicAdd(lp + 32, lb2);
    }
}

// ---- out[b, h*64+v, xy] = sum_k qbn[b,hk,xy] * lam[b,hk,v]. ----
__global__ __launch_bounds__(256) void out_kernel(
    const float* __restrict__ qbn, const float* __restrict__ lam,
    float* __restrict__ out)
{
    int t = threadIdx.x;
    int b = blockIdx.x >> 4, s = blockIdx.x & 15;
    int h = s >> 2, qc = s & 3;
    int xy = qc * 1024 + t * 4;
    float4 q0 = *(const float4*)(qbn + ((size_t)b * 16 + h * 4 + 0) * WH + xy);
    float4 q1 = *(const float4*)(qbn + ((size_t)b * 16 + h * 4 + 1) * WH + xy);
    float4 q2 = *(const float4*)(qbn + ((size_t)b * 16 + h * 4 + 2) * WH + xy);
    float4 q3 = *(const float4*)(qbn + ((size_t)b * 16 + h * 4 + 3) * WH + xy);
    const float* lb = lam + (size_t)b * 1024 + (size_t)h * 256;
    float* ob = out + ((size_t)b * 256 + (size_t)h * 64) * WH + xy;
#pragma unroll 8
    for (int v = 0; v < 64; ++v) {
        float l0 = lb[v], l1 = lb[64 + v], l2 = lb[128 + v], l3 = lb[192 + v];
        float4 o;
        o.x = q0.x*l0 + q1.x*l1 + q2.x*l2 + q3.x*l3;
        o.y = q0.y*l0 + q1.y*l1 + q2.y*l2 + q3.y*l3;
        o.z = q0.z*l0 + q1.z*l1 + q2.z*l2 + q3.z*l3;
        o.w = q0.w*l0 + q1.w*l1 + q2.w*l2 + q3.w*l3;
        *(float4*)(ob + (size_t)v * WH) = o;
    }
}

extern "C" void kernel_launch(void* const* d_in, const int* in_sizes, int n_in,
                              void* d_out, int out_size, void* d_ws, size_t ws_size,
                              hipStream_t stream)
{
    const float* x   = (const float*)d_in[0];
    const float* qw  = (const float*)d_in[1];
    const float* qg  = (const float*)d_in[2];
    const float* qb  = (const float*)d_in[3];
    const float* qm  = (const float*)d_in[4];
    const float* qv  = (const float*)d_in[5];
    const float* kw  = (const float*)d_in[6];
    const float* kg  = (const float*)d_in[7];
    const float* kb  = (const float*)d_in[8];
    const float* km  = (const float*)d_in[9];
    const float* kv  = (const float*)d_in[10];
    const float* vw  = (const float*)d_in[11];
    const float* emb = (const float*)d_in[12];

    float* ws     = (float*)d_ws;
    float* qbn    = ws;
    float* kkbn   = ws + 1048576;
    float* pstats = ws + 2097152;
    float* Wt     = ws + 2105344;
    float* lam    = ws + 2170880;
    float* out    = (float*)d_out;

    hipLaunchKernelGGL(proj_kernel,  dim3(320), dim3(512), 0, stream,
                       x, qw, kw, qg, qb, qm, qv, kg, kb, km, kv, emb,
                       qbn, kkbn, pstats, Wt, lam);
    hipLaunchKernelGGL(ut_kernel,    dim3(512), dim3(512), 0, stream,
                       x, kkbn, pstats, Wt, vw, lam);
    hipLaunchKernelGGL(out_kernel,   dim3(256), dim3(256), 0, stream, qbn, lam, out);
}

// Round 7
// 76.035 us; speedup vs baseline: 1.5976x; 1.5976x over previous
//
#include <hip/hip_runtime.h>
#include <math.h>

#define C_   256
#define WH   4096

typedef _Float16 f16x8 __attribute__((ext_vector_type(8)));
typedef float    f32x4 __attribute__((ext_vector_type(4)));

// ---------------- workspace layout (floats) ----------------
// qbn   : [16][16][4096]           @ 0          (1,048,576)
// kkbn  : [16][16][4096]           @ 1,048,576  (1,048,576)
// pstats: [256 rows][16 chunk][2]  @ 2,097,152  (8,192)
// Wt    : [16][4096]               @ 2,105,344  (65,536)
// Mpart : [16][32 seg][16][256]    @ 2,170,880  (2,097,152)   merged U+T rows

// ---- q/k 1x1 projections + BN + per-chunk softmax partials (blocks 0..255)
//      + Wt generation (blocks 256..319). ----
__global__ __launch_bounds__(512) void proj_kernel(
    const float* __restrict__ x,
    const float* __restrict__ qw, const float* __restrict__ kw,
    const float* __restrict__ qg, const float* __restrict__ qb,
    const float* __restrict__ qm, const float* __restrict__ qv,
    const float* __restrict__ kg, const float* __restrict__ kb,
    const float* __restrict__ km, const float* __restrict__ kv,
    const float* __restrict__ emb,
    float* __restrict__ qbn, float* __restrict__ kkbn,
    float* __restrict__ pstats, float* __restrict__ Wt)
{
    if (blockIdx.x >= 256) {
        // ---- Wt: summed spatial weight of the positional conv ----
        int wb = blockIdx.x - 256;
        int hk = wb >> 2, quarter = wb & 3;
        int h = hk >> 2, k = hk & 3;
        const float* e = emb + (size_t)(k * 4 + h) * 529;   // emb[k][h][0][0][i][j]
        __shared__ float colsum[23][64];
        for (int t2 = threadIdx.x; t2 < 23 * 64; t2 += 512) {
            int i = t2 / 64, q = t2 % 64;
            int jlo = max(0, q - 52), jhi = min(22, q + 11);
            float s = 0.f;
            for (int j = jlo; j <= jhi; ++j) s += e[i * 23 + j];
            colsum[i][q] = s;
        }
        __syncthreads();
        for (int tt = threadIdx.x; tt < 1024; tt += 512) {
            int t2 = quarter * 1024 + tt;
            int p = t2 >> 6, q = t2 & 63;
            int ilo = max(0, p - 52), ihi = min(22, p + 11);
            float s = 0.f;
            for (int i = ilo; i <= ihi; ++i) s += colsum[i][q];
            Wt[(size_t)hk * WH + t2] = s;
        }
        return;
    }

    int t = threadIdx.x;
    int b = blockIdx.x >> 4, chunk = blockIdx.x & 15;
    int lane = t & 63;
    int og = __builtin_amdgcn_readfirstlane(t >> 6);   // 0..7, wave-uniform
    int isK = og >> 2;
    int o4 = (og & 3) * 4;
    int xy = chunk * 256 + lane * 4;

    const float* wsrc = isK ? kw : qw;
    const float* w0 = wsrc + (size_t)(o4 + 0) * 256;
    const float* w1 = wsrc + (size_t)(o4 + 1) * 256;
    const float* w2 = wsrc + (size_t)(o4 + 2) * 256;
    const float* w3 = wsrc + (size_t)(o4 + 3) * 256;

    float4 a0 = {0,0,0,0}, a1 = {0,0,0,0}, a2 = {0,0,0,0}, a3 = {0,0,0,0};
    const float* xb = x + (size_t)b * C_ * WH + xy;
#pragma unroll 8
    for (int c = 0; c < 256; ++c) {
        float4 xv = *(const float4*)(xb + (size_t)c * WH);
        float f0 = w0[c], f1 = w1[c], f2 = w2[c], f3 = w3[c];
        a0.x += xv.x*f0; a0.y += xv.y*f0; a0.z += xv.z*f0; a0.w += xv.w*f0;
        a1.x += xv.x*f1; a1.y += xv.y*f1; a1.z += xv.z*f1; a1.w += xv.w*f1;
        a2.x += xv.x*f2; a2.y += xv.y*f2; a2.z += xv.z*f2; a2.w += xv.w*f2;
        a3.x += xv.x*f3; a3.y += xv.y*f3; a3.z += xv.z*f3; a3.w += xv.w*f3;
    }
    float4 acc4[4] = {a0, a1, a2, a3};

    if (!isK) {
#pragma unroll
        for (int i = 0; i < 4; ++i) {
            int hk = o4 + i;
            float s  = qg[hk] * rsqrtf(qv[hk] + 1e-5f);
            float tq = qb[hk] - qm[hk] * s;
            float4 a = acc4[i], o;
            o.x = a.x * s + tq; o.y = a.y * s + tq;
            o.z = a.z * s + tq; o.w = a.w * s + tq;
            *(float4*)(qbn + ((size_t)b * 16 + hk) * WH + xy) = o;
        }
    } else {
#pragma unroll
        for (int i = 0; i < 4; ++i) {
            int hk = o4 + i;
            float s2 = kg[hk] * rsqrtf(kv[hk] + 1e-5f);
            float tk = kb[hk] - km[hk] * s2;
            float4 a = acc4[i], o;
            o.x = a.x * s2 + tk; o.y = a.y * s2 + tk;
            o.z = a.z * s2 + tk; o.w = a.w * s2 + tk;
            *(float4*)(kkbn + ((size_t)b * 16 + hk) * WH + xy) = o;
            float m = fmaxf(fmaxf(o.x, o.y), fmaxf(o.z, o.w));
#pragma unroll
            for (int off = 32; off; off >>= 1) m = fmaxf(m, __shfl_xor(m, off, 64));
            float e = __expf(o.x - m) + __expf(o.y - m) + __expf(o.z - m) + __expf(o.w - m);
#pragma unroll
            for (int off = 32; off; off >>= 1) e += __shfl_xor(e, off, 64);
            if (lane == 0) {
                float* ps = pstats + ((size_t)(b * 16 + hk) * 16 + chunk) * 2;
                ps[0] = m; ps[1] = e;
            }
        }
    }
}

// ---- U/T contractions via fp16 MFMA (fp32 accumulate).
// Grid 512 = (b, s5 of 128 xy), 2 blocks/CU. Round-5 proven body; only the
// tail differs: U (rows r) and T (rows 16+r) are merged IN-REGISTER (same
// lane, same column) and a 16x256 merged tile is written (half the traffic). ----
__global__ __launch_bounds__(512) void ut_kernel(
    const float* __restrict__ x, const float* __restrict__ kkbn,
    const float* __restrict__ pstats, const float* __restrict__ Wt,
    float* __restrict__ Mpart)
{
    __shared__ _Float16 xls[256][72];   // 36,864 B : X rows (c), 64 k per chunk
    __shared__ _Float16 wls[32][72];    //  4,608 B : W rows (r), 64 k per chunk
    __shared__ float st[32];            // M, 1/S per sm row
    int t = threadIdx.x;
    int b = blockIdx.x >> 5, s5 = blockIdx.x & 31;
    int xys0 = s5 * 128;
    int lane = t & 63;
    int wid = __builtin_amdgcn_readfirstlane(t >> 6);   // 0..7
    int r16 = lane & 15, g = lane >> 4;
    int n0 = wid * 32;

    // ---- inline softmax-stats combine: thread r<16 handles row r ----
    if (t < 16) {
        const float* ps = pstats + (size_t)(b * 16 + t) * 32;
        float M = ps[0];
#pragma unroll
        for (int ch = 1; ch < 16; ++ch) M = fmaxf(M, ps[ch * 2]);
        float S = 0.f;
#pragma unroll
        for (int ch = 0; ch < 16; ++ch) S += ps[ch * 2 + 1] * __expf(ps[ch * 2] - M);
        st[2 * t]     = M;
        st[2 * t + 1] = 1.f / S;
    }

    // staging coords
    int sc = t >> 1, shalf = t & 1;                 // x: row sc, 32-col half
    int wr = t >> 3, wco = (t & 7) * 8;             // w: row wr (t<256 only)

    f32x4 acc00 = {0.f,0.f,0.f,0.f}, acc01 = {0.f,0.f,0.f,0.f};
    f32x4 acc10 = {0.f,0.f,0.f,0.f}, acc11 = {0.f,0.f,0.f,0.f};

    for (int ch = 0; ch < 2; ++ch) {
        int kbase = xys0 + ch * 64;
        __syncthreads();                            // st[] visible / prev reads done
        {   // stage X: 256 rows x 64 k  (thread: row sc, cols shalf*32..+31)
            const float* xp = x + ((size_t)b * C_ + sc) * WH + kbase + shalf * 32;
#pragma unroll
            for (int j = 0; j < 4; ++j) {
                float4 u  = *(const float4*)(xp + j * 8);
                float4 u2 = *(const float4*)(xp + j * 8 + 4);
                f16x8 o;
                o[0] = (_Float16)u.x;  o[1] = (_Float16)u.y;
                o[2] = (_Float16)u.z;  o[3] = (_Float16)u.w;
                o[4] = (_Float16)u2.x; o[5] = (_Float16)u2.y;
                o[6] = (_Float16)u2.z; o[7] = (_Float16)u2.w;
                *(f16x8*)&xls[sc][shalf * 32 + j * 8] = o;
            }
        }
        if (t < 256) {  // stage W: rows 0..15 = sm(kkbn), 16..31 = Wt
            f16x8 o;
            if (wr < 16) {
                float wm   = st[2 * wr];
                float winv = st[2 * wr + 1];
                const float* src = kkbn + ((size_t)b * 16 + wr) * WH + kbase + wco;
                float4 u  = *(const float4*)(src);
                float4 u2 = *(const float4*)(src + 4);
                o[0] = (_Float16)(__expf(u.x  - wm) * winv);
                o[1] = (_Float16)(__expf(u.y  - wm) * winv);
                o[2] = (_Float16)(__expf(u.z  - wm) * winv);
                o[3] = (_Float16)(__expf(u.w  - wm) * winv);
                o[4] = (_Float16)(__expf(u2.x - wm) * winv);
                o[5] = (_Float16)(__expf(u2.y - wm) * winv);
                o[6] = (_Float16)(__expf(u2.z - wm) * winv);
                o[7] = (_Float16)(__expf(u2.w - wm) * winv);
            } else {
                const float* src = Wt + (size_t)(wr - 16) * WH + kbase + wco;
                float4 u  = *(const float4*)(src);
                float4 u2 = *(const float4*)(src + 4);
                o[0] = (_Float16)u.x;  o[1] = (_Float16)u.y;
                o[2] = (_Float16)u.z;  o[3] = (_Float16)u.w;
                o[4] = (_Float16)u2.x; o[5] = (_Float16)u2.y;
                o[6] = (_Float16)u2.z; o[7] = (_Float16)u2.w;
            }
            *(f16x8*)&wls[wr][wco] = o;
        }
        __syncthreads();                            // tile visible
#pragma unroll
        for (int s = 0; s < 2; ++s) {
            int koff = s * 32 + g * 8;
            f16x8 A0 = *(const f16x8*)&wls[r16     ][koff];
            f16x8 A1 = *(const f16x8*)&wls[16 + r16][koff];
            f16x8 B0 = *(const f16x8*)&xls[n0 + r16     ][koff];
            f16x8 B1 = *(const f16x8*)&xls[n0 + 16 + r16][koff];
            acc00 = __builtin_amdgcn_mfma_f32_16x16x32_f16(A0, B0, acc00, 0, 0, 0);
            acc01 = __builtin_amdgcn_mfma_f32_16x16x32_f16(A0, B1, acc01, 0, 0, 0);
            acc10 = __builtin_amdgcn_mfma_f32_16x16x32_f16(A1, B0, acc10, 0, 0, 0);
            acc11 = __builtin_amdgcn_mfma_f32_16x16x32_f16(A1, B1, acc11, 0, 0, 0);
        }
    }

    // ---- merged write: row r = U_r + T_r (acc00+acc10 / acc01+acc11) ----
    // D layout: row = g*4 + reg, col = n0 (+16) + r16
    float* mp = Mpart + (size_t)(b * 32 + s5) * 4096;
    int colA = n0 + r16, colB = n0 + 16 + r16;
    int row0 = g * 4;
#pragma unroll
    for (int rr = 0; rr < 4; ++rr) {
        mp[(row0 + rr) * 256 + colA] = acc00[rr] + acc10[rr];
        mp[(row0 + rr) * 256 + colB] = acc01[rr] + acc11[rr];
    }
}

// ---- fused lambda + out. Block = (b, h, xy-quarter), 256 thr.
// Phase 1: stage vw[h] in LDS (coalesced) + sum merged Mpart rows h*4..h*4+3
// over 32 segs (coalesced). Phase 2: lam[4][64] contraction entirely in LDS.
// Phase 3: out[b, h*64+v, xy] = sum_k qbn[b,hk,xy] * lam[k][v]. ----
__global__ __launch_bounds__(256) void out_kernel(
    const float* __restrict__ qbn, const float* __restrict__ Mpart,
    const float* __restrict__ vw, float* __restrict__ out)
{
    __shared__ float vls[64][260];   // 66,560 B (pad: rows start 8 bank-quads apart)
    __shared__ float msum[4][256];
    __shared__ float lam_s[4][64];
    int t = threadIdx.x;
    int b = blockIdx.x >> 4, s = blockIdx.x & 15;
    int h = s >> 2, qc = s & 3;

    {   // stage vw[h]: 64 v x 256 c, coalesced float4
        const float* vwh = vw + (size_t)h * 64 * 256;
#pragma unroll
        for (int i = 0; i < 16; ++i) {
            int e = t + i * 256;              // float4 index in [0,4096)
            int vv = e >> 6, c4 = (e & 63) * 4;
            *(float4*)&vls[vv][c4] = *(const float4*)(vwh + (size_t)vv * 256 + c4);
        }
    }
    {   // msum[rr][c] = sum_seg Mpart[b][seg][h*4+rr][c]  (coalesced, c = t)
        const float* mp = Mpart + (size_t)b * 32 * 4096 + t;
#pragma unroll
        for (int rr = 0; rr < 4; ++rr) {
            const float* m2 = mp + (h * 4 + rr) * 256;
            float ssum = 0.f;
            for (int seg = 0; seg < 32; ++seg) ssum += m2[seg * 4096];
            msum[rr][t] = ssum;
        }
    }
    __syncthreads();
    {   // lam_s[rr][v] = sum_c msum[rr][c] * vls[v][c]
        int rr = t >> 6, v = t & 63;
        float acc = 0.f;
#pragma unroll 8
        for (int c4 = 0; c4 < 64; ++c4) {
            float4 a = *(const float4*)&vls[v][c4 * 4];
            float4 m = *(const float4*)&msum[rr][c4 * 4];
            acc += a.x*m.x + a.y*m.y + a.z*m.z + a.w*m.w;
        }
        lam_s[rr][v] = acc;
    }
    __syncthreads();

    int xy = qc * 1024 + t * 4;
    float4 q0 = *(const float4*)(qbn + ((size_t)b * 16 + h * 4 + 0) * WH + xy);
    float4 q1 = *(const float4*)(qbn + ((size_t)b * 16 + h * 4 + 1) * WH + xy);
    float4 q2 = *(const float4*)(qbn + ((size_t)b * 16 + h * 4 + 2) * WH + xy);
    float4 q3 = *(const float4*)(qbn + ((size_t)b * 16 + h * 4 + 3) * WH + xy);
    float* ob = out + ((size_t)b * 256 + (size_t)h * 64) * WH + xy;
#pragma unroll 8
    for (int v = 0; v < 64; ++v) {
        float l0 = lam_s[0][v], l1 = lam_s[1][v], l2 = lam_s[2][v], l3 = lam_s[3][v];
        float4 o;
        o.x = q0.x*l0 + q1.x*l1 + q2.x*l2 + q3.x*l3;
        o.y = q0.y*l0 + q1.y*l1 + q2.y*l2 + q3.y*l3;
        o.z = q0.z*l0 + q1.z*l1 + q2.z*l2 + q3.z*l3;
        o.w = q0.w*l0 + q1.w*l1 + q2.w*l2 + q3.w*l3;
        *(float4*)(ob + (size_t)v * WH) = o;
    }
}

extern "C" void kernel_launch(void* const* d_in, const int* in_sizes, int n_in,
                              void* d_out, int out_size, void* d_ws, size_t ws_size,
                              hipStream_t stream)
{
    const float* x   = (const float*)d_in[0];
    const float* qw  = (const float*)d_in[1];
    const float* qg  = (const float*)d_in[2];
    const float* qb  = (const float*)d_in[3];
    const float* qm  = (const float*)d_in[4];
    const float* qv  = (const float*)d_in[5];
    const float* kw  = (const float*)d_in[6];
    const float* kg  = (const float*)d_in[7];
    const float* kb  = (const float*)d_in[8];
    const float* km  = (const float*)d_in[9];
    const float* kv  = (const float*)d_in[10];
    const float* vw  = (const float*)d_in[11];
    const float* emb = (const float*)d_in[12];

    float* ws     = (float*)d_ws;
    float* qbn    = ws;
    float* kkbn   = ws + 1048576;
    float* pstats = ws + 2097152;
    float* Wt     = ws + 2105344;
    float* Mpart  = ws + 2170880;
    float* out    = (float*)d_out;

    hipLaunchKernelGGL(proj_kernel,  dim3(320), dim3(512), 0, stream,
                       x, qw, kw, qg, qb, qm, qv, kg, kb, km, kv, emb,
                       qbn, kkbn, pstats, Wt);
    hipLaunchKernelGGL(ut_kernel,    dim3(512), dim3(512), 0, stream,
                       x, kkbn, pstats, Wt, Mpart);
    hipLaunchKernelGGL(out_kernel,   dim3(256), dim3(256), 0, stream,
                       qbn, Mpart, vw, out);
}